// Round 11
// baseline (62.562 us; speedup 1.0000x reference)
//
#include <hip/hip_runtime.h>
#include <cfloat>

#define B_ 32
#define N_ 1000
#define K_ 10
#define H_ 128
#define C_ 2
#define NFEAT 43
#define QPB 16      // queries per block
#define TPQ 16      // lanes per query -> 8000 waves total (2x R7)
#define G_ 16
#define CW (1.0f / 16.0f)
#define RING0 2     // 5x5 cell box

// ws layout (bytes): [0,22016) Meff | [22016,278016) spts float2
//                    | [278016,406016) skey int | [406016,438912) cellstart int
#define WS_MEFF   0
#define WS_SPTS   22016
#define WS_SKEY   278016
#define WS_CSTART 406016
#define WS_NEED   438912

// ---------------------------------------------------------------------------
// meff row computation (shared by prep and standalone build_meff)
// ---------------------------------------------------------------------------
__device__ __forceinline__ void meff_row(
    int r, int g, const float* __restrict__ Wx, const float* __restrict__ bx,
    const float* __restrict__ Wy, const float* __restrict__ by,
    const float* __restrict__ W1, const float* __restrict__ b1,
    const float* __restrict__ W2, const float* __restrict__ b2,
    float* __restrict__ M) {
  float acc = 0.f;
  if (r < 40) {
    const int rp = (r < 20) ? r : r - 20;
    const float* W = (r < 20) ? Wx : Wy;
    const int k = rp >> 1;
    const int c = rp & 1;
    const float* Wcol = W + c * K_ + k;
    for (int h = 0; h < H_; ++h)
      acc = fmaf(Wcol[h * C_ * K_], W2[h * H_ + g], acc);
  } else if (r < 42) {
    acc = W1[(r - 40) * H_ + g];
  } else {
    for (int h = 0; h < H_; ++h)
      acc = fmaf(bx[h] + by[h], W2[h * H_ + g], acc);
    acc += b1[g] + b2[g];
  }
  M[r * H_ + g] = acc;
}

__global__ __launch_bounds__(H_) void build_meff(
    const float* __restrict__ Wx, const float* __restrict__ bx,
    const float* __restrict__ Wy, const float* __restrict__ by,
    const float* __restrict__ W1, const float* __restrict__ b1,
    const float* __restrict__ W2, const float* __restrict__ b2,
    float* __restrict__ M) {
  meff_row(blockIdx.x, threadIdx.x, Wx, bx, Wy, by, W1, b1, W2, b2, M);
}

// ---------------------------------------------------------------------------
// Prep (fused): blocks 0..31 = per-batch counting sort; 32..74 = meff rows.
// ---------------------------------------------------------------------------
__global__ __launch_bounds__(256) void prep(
    const float* __restrict__ x,
    const float* __restrict__ Wx, const float* __restrict__ bx,
    const float* __restrict__ Wy, const float* __restrict__ by,
    const float* __restrict__ W1, const float* __restrict__ b1,
    const float* __restrict__ W2, const float* __restrict__ b2,
    float* __restrict__ Meff, float2* __restrict__ spts_g,
    int* __restrict__ skey_g, int* __restrict__ cstart_g) {
  const int tid = threadIdx.x;
  if (blockIdx.x >= B_) {
    const int r = blockIdx.x - B_;
    if (tid < H_) meff_row(r, tid, Wx, bx, Wy, by, W1, b1, W2, b2, Meff);
    return;
  }
  const int b = blockIdx.x;
  __shared__ float2 p[N_];
  __shared__ short  cidv[N_];
  __shared__ int    hist[G_ * G_], scn[G_ * G_], cur[G_ * G_];

  const float2* xb = (const float2*)(x + (size_t)b * N_ * C_);
  hist[tid] = 0;
  __syncthreads();
  for (int i = tid; i < N_; i += 256) {
    float2 v = xb[i];
    p[i] = v;
    int cxx = min(G_ - 1, max(0, (int)(v.x * (float)G_)));
    int cyy = min(G_ - 1, max(0, (int)(v.y * (float)G_)));
    int c = cyy * G_ + cxx;
    cidv[i] = (short)c;
    atomicAdd(&hist[c], 1);
  }
  __syncthreads();
  const int v = hist[tid];
  scn[tid] = v;
  __syncthreads();
  for (int off = 1; off < G_ * G_; off <<= 1) {
    int add = (tid >= off) ? scn[tid - off] : 0;
    __syncthreads();
    scn[tid] += add;
    __syncthreads();
  }
  const int excl = scn[tid] - v;
  cur[tid] = excl;
  cstart_g[b * (G_ * G_ + 1) + tid] = excl;
  if (tid == 0) cstart_g[b * (G_ * G_ + 1) + G_ * G_] = N_;
  __syncthreads();
  for (int i = tid; i < N_; i += 256) {
    int c = cidv[i];
    int pos = atomicAdd(&cur[c], 1);
    spts_g[b * N_ + pos] = p[i];
    skey_g[b * N_ + pos] = (i << 16) | pos;   // (orig_idx:16 | sorted_pos:16)
  }
}

// ---------------------------------------------------------------------------
// shuffle helpers + bubble pair-merge (proven R7)
// ---------------------------------------------------------------------------
__device__ __forceinline__ unsigned long long shflx64(unsigned long long v, int msk) {
  const unsigned lo = __shfl_xor((unsigned)(v & 0xffffffffull), msk, 64);
  const unsigned hi = __shfl_xor((unsigned)(v >> 32), msk, 64);
  return ((unsigned long long)hi << 32) | lo;
}

// pairwise merge of two sorted-ascending 10-lists held by xor-partner lanes;
// D_i = min(A_i, B_{9-i}) is exactly the 10 smallest of A∪B (keys unique),
// then a bubble network restores ascending order. Both lanes get the result.
__device__ __forceinline__ void pair_merge(unsigned long long (&bk)[K_], int msk) {
  unsigned long long prt[K_];
#pragma unroll
  for (int e = 0; e < K_; ++e) prt[e] = shflx64(bk[e], msk);
  unsigned long long mg[K_];
#pragma unroll
  for (int e = 0; e < K_; ++e) {
    const unsigned long long o = prt[K_ - 1 - e];
    mg[e] = bk[e] < o ? bk[e] : o;
  }
#pragma unroll
  for (int p = 0; p < K_ - 1; ++p) {
#pragma unroll
    for (int u = 0; u < K_ - 1 - p; ++u) {
      const unsigned long long a = mg[u], c = mg[u + 1];
      const bool sw = c < a;
      mg[u]     = sw ? c : a;
      mg[u + 1] = sw ? a : c;
    }
  }
#pragma unroll
  for (int e = 0; e < K_; ++e) bk[e] = mg[e];
}

// branchless rank-insert (u64 key = (d2,orig,spos) => exact lax.top_k order)
#define INSERT_LDS(j)                                                          \
  {                                                                            \
    const float2 pp = spts[(j)];                                               \
    const float dx = __fsub_rn(px, pp.x);                                      \
    const float dy = __fsub_rn(py, pp.y);                                      \
    const float dd = __fadd_rn(__fmul_rn(dx, dx), __fmul_rn(dy, dy));          \
    const unsigned long long key =                                             \
        ((unsigned long long)__float_as_uint(dd) << 32) | (unsigned)skey[(j)]; \
    bool c[K_];                                                                \
    _Pragma("unroll") for (int kk = 0; kk < K_; ++kk) c[kk] = key < bk[kk];    \
    _Pragma("unroll") for (int kk = K_ - 1; kk >= 1; --kk)                     \
        bk[kk] = c[kk - 1] ? bk[kk - 1] : (c[kk] ? key : bk[kk]);              \
    bk[0] = c[0] ? key : bk[0];                                                \
  }

// ---------------------------------------------------------------------------
// Kernel C: grid-pruned exact KNN. LDS scan (13 KB only — M stays in global
// so LDS doesn't cap blocks/CU), TPQ=16 -> 8000 waves (~7.9/CU supplied at
// 256 thr/block), bubble shuffle tree merge, per-query uniform rare retry,
// all-lane redundant feat + fused affine with M float4 from global (L1-hot).
// grid = (63, 32). NOTE: no min-waves hint > 4 — VGPR caps below ~60 spill
// wholesale (R6/R8: WRITE_SIZE 16->76/108 MB).
// ---------------------------------------------------------------------------
__global__ __launch_bounds__(QPB * TPQ, 4) void conv_knn(
    const float2* __restrict__ spts_g, const int* __restrict__ skey_g,
    const int* __restrict__ cstart_g, const float* __restrict__ Meff,
    float* __restrict__ out) {
  __shared__ float2 spts[N_];                 // 8 KB
  __shared__ int    skey[N_];                 // 4 KB
  __shared__ int    cstart[G_ * G_ + 1];      // 1 KB

  const int b = blockIdx.y, tid = threadIdx.x;
  const int q = tid >> 4, t = tid & 15;
  const int s = blockIdx.x * QPB + q;
  const bool valid = (s < N_);

  const float2* spg = spts_g + (size_t)b * N_;
  const int*    skg = skey_g + (size_t)b * N_;
  for (int i = tid; i < N_; i += QPB * TPQ) { spts[i] = spg[i]; skey[i] = skg[i]; }
  for (int i = tid; i < G_ * G_ + 1; i += QPB * TPQ)
    cstart[i] = cstart_g[b * (G_ * G_ + 1) + i];
  __syncthreads();

  float px = 0.f, py = 0.f;
  int cx = 0, cy = 0;
  if (valid) {
    px = spts[s].x; py = spts[s].y;
    cx = min(G_ - 1, max(0, (int)(px * (float)G_)));
    cy = min(G_ - 1, max(0, (int)(py * (float)G_)));
  }

  unsigned long long bk[K_];
#pragma unroll
  for (int k = 0; k < K_; ++k) bk[k] = ~0ull;

  // ---- single-pass 5x5 box scan, 16-way sliced per query ----
  const int X0 = max(cx - RING0, 0), X1 = min(cx + RING0, G_ - 1);
  const int Y0 = max(cy - RING0, 0), Y1 = min(cy + RING0, G_ - 1);
  if (valid) {
    for (int yy = Y0; yy <= Y1; ++yy) {
      const int s0 = cstart[yy * G_ + X0];
      const int s1 = cstart[yy * G_ + X1 + 1];
      for (int j = s0 + t; j < s1; j += TPQ) INSERT_LDS(j);
    }
  }

  // ---- shuffle tree merge: 4 levels -> all 16 lanes hold merged sorted
  // top-10 (unguarded: all 64 lanes active for shuffles) ----
  pair_merge(bk, 1);
  pair_merge(bk, 2);
  pair_merge(bk, 4);
  pair_merge(bk, 8);

  // ---- exact termination test (identical across a query's 16 lanes) ----
  bool done = true;
  if (valid) {
    const unsigned long long last = bk[K_ - 1];
    const bool have10 = (last != ~0ull);
    const float tau = __uint_as_float((unsigned)(last >> 32));
    float R = 1e30f;
    if (X0 > 0)      R = fminf(R, px - (float)X0 * CW);
    if (X1 < G_ - 1) R = fminf(R, (float)(X1 + 1) * CW - px);
    if (Y0 > 0)      R = fminf(R, py - (float)Y0 * CW);
    if (Y1 < G_ - 1) R = fminf(R, (float)(Y1 + 1) * CW - py);
    const bool fullg = (X0 == 0) && (X1 == G_ - 1) && (Y0 == 0) && (Y1 == G_ - 1);
    const float Rs = R - 1e-6f;   // margin vs. cell-assignment rounding
    done = fullg || (have10 && Rs > 0.f && tau < Rs * Rs);
  }

  // ---- rare exact retry (query-uniform predicate; shuffles stay in-group) ----
  if (!done) {
#pragma unroll
    for (int k = 0; k < K_; ++k) bk[k] = ~0ull;
    for (int j = t; j < N_; j += TPQ) INSERT_LDS(j);
    pair_merge(bk, 1);
    pair_merge(bk, 2);
    pair_merge(bk, 4);
    pair_merge(bk, 8);
  }

  // ---- gather coords into feat + in-place stable bubble sorts (all lanes,
  // redundant: no serial tail, no extra LDS) ----
  float feat[NFEAT];
  if (valid) {
#pragma unroll
    for (int k = 0; k < K_; ++k) {
      const int spos = (int)(bk[k] & 0xffffull);
      const float2 c = spts[spos];
      feat[2 * k]          = c.x;
      feat[2 * k + 1]      = c.y;
      feat[20 + 2 * k]     = c.x;
      feat[20 + 2 * k + 1] = c.y;
    }
    // sort pairs (feat[2k],feat[2k+1]) by x  (strict swap => stable)
#pragma unroll
    for (int p = 0; p < K_ - 1; ++p) {
#pragma unroll
      for (int u = 0; u < K_ - 1 - p; ++u) {
        const bool sw = feat[2 * u + 2] < feat[2 * u];
        const float ax = feat[2 * u], ay = feat[2 * u + 1];
        feat[2 * u]     = sw ? feat[2 * u + 2] : ax;
        feat[2 * u + 1] = sw ? feat[2 * u + 3] : ay;
        feat[2 * u + 2] = sw ? ax : feat[2 * u + 2];
        feat[2 * u + 3] = sw ? ay : feat[2 * u + 3];
      }
    }
    // sort pairs (feat[20+2k],feat[20+2k+1]) by y
#pragma unroll
    for (int p = 0; p < K_ - 1; ++p) {
#pragma unroll
      for (int u = 0; u < K_ - 1 - p; ++u) {
        const int e = 20 + 2 * u;
        const bool sw = feat[e + 3] < feat[e + 1];
        const float ax = feat[e], ay = feat[e + 1];
        feat[e]     = sw ? feat[e + 2] : ax;
        feat[e + 1] = sw ? feat[e + 3] : ay;
        feat[e + 2] = sw ? ax : feat[e + 2];
        feat[e + 3] = sw ? ay : feat[e + 3];
      }
    }
    feat[40] = px;
    feat[41] = py;
    feat[42] = 1.f;

    // ---- fused affine: M float4 from global (22 KB, L1-hot; 16 lanes read
    // 16 consecutive float4 = 256B coalesced, broadcast across the wave's 4
    // queries). Thread t, chunk j covers g = j*64 + 4t. ----
    const int otar = skey[s] >> 16;
    float* op = out + ((size_t)(b * N_ + otar)) * H_;
    const float4* M4 = (const float4*)Meff;   // row r = 32 float4
#pragma unroll
    for (int j = 0; j < 2; ++j) {
      float4 acc = make_float4(0.f, 0.f, 0.f, 0.f);
#pragma unroll
      for (int r = 0; r < NFEAT; ++r) {
        const float4 m = M4[r * 32 + j * 16 + t];
        acc.x = fmaf(feat[r], m.x, acc.x);
        acc.y = fmaf(feat[r], m.y, acc.y);
        acc.z = fmaf(feat[r], m.z, acc.z);
        acc.w = fmaf(feat[r], m.w, acc.w);
      }
      *(float4*)&op[j * 64 + 4 * t] = acc;
    }
  }
}
#undef INSERT_LDS

// ---------------------------------------------------------------------------
// No-workspace fallback (round-2 kernel).
// ---------------------------------------------------------------------------
#define LSTRIDE 170
__global__ __launch_bounds__(256, 4) void conv_emb_fb(
    const float* __restrict__ x, const float* __restrict__ Meff,
    float* __restrict__ out) {
  __shared__ float2 pts[N_];
  __shared__ float  smem[NFEAT * H_];
  __shared__ int    midx[32 * K_];

  const int b   = blockIdx.y;
  const int tid = threadIdx.x;
  const int q   = tid >> 3;
  const int t   = tid & 7;
  const int n   = blockIdx.x * 32 + q;
  const bool valid = (n < N_);

  const float2* xb = (const float2*)(x + (size_t)b * N_ * C_);
  for (int i = tid; i < N_; i += 256) pts[i] = xb[i];
  __syncthreads();

  float px = 0.f, py = 0.f;
  if (valid) { px = pts[n].x; py = pts[n].y; }

  float bd[K_]; int bi[K_];
#pragma unroll
  for (int k = 0; k < K_; ++k) { bd[k] = FLT_MAX; bi[k] = 0; }

#pragma unroll 2
  for (int m = 0; m < N_ / 8; ++m) {
    const int j = t + m * 8;
    const float2 p = pts[j];
    const float dx = __fsub_rn(px, p.x);
    const float dy = __fsub_rn(py, p.y);
    const float d  = __fadd_rn(__fmul_rn(dx, dx), __fmul_rn(dy, dy));
    bool c[K_];
#pragma unroll
    for (int s = 0; s < K_; ++s) c[s] = d < bd[s];
#pragma unroll
    for (int s = K_ - 1; s >= 1; --s) {
      bd[s] = c[s - 1] ? bd[s - 1] : (c[s] ? d : bd[s]);
      bi[s] = c[s - 1] ? bi[s - 1] : (c[s] ? j : bi[s]);
    }
    bd[0] = c[0] ? d : bd[0];
    bi[0] = c[0] ? j : bi[0];
  }

  const int lbase = q * LSTRIDE + t * 2 * K_;
#pragma unroll
  for (int e = 0; e < K_; ++e) {
    smem[lbase + 2 * e]     = bd[e];
    smem[lbase + 2 * e + 1] = __int_as_float(bi[e]);
  }
  __syncthreads();

  if (t == 0 && valid) {
    int cc[8];
#pragma unroll
    for (int tt = 0; tt < 8; ++tt) cc[tt] = 0;
    const int mb = q * LSTRIDE;
#pragma unroll
    for (int s = 0; s < K_; ++s) {
      float bdv = FLT_MAX; int biv = 0x7fffffff; int bt = 0;
#pragma unroll
      for (int tt = 0; tt < 8; ++tt) {
        const int off = mb + tt * 2 * K_ + cc[tt] * 2;
        const float hd = smem[off];
        const int   hi = __float_as_int(smem[off + 1]);
        const bool take = (hd < bdv) || ((hd == bdv) && (hi < biv));
        bdv = take ? hd : bdv;
        biv = take ? hi : biv;
        bt  = take ? tt : bt;
      }
      midx[q * K_ + s] = biv;
#pragma unroll
      for (int tt = 0; tt < 8; ++tt) cc[tt] += (bt == tt) ? 1 : 0;
    }
  }
  __syncthreads();

  int ridx[K_];
  if (valid) {
#pragma unroll
    for (int k = 0; k < K_; ++k) ridx[k] = midx[q * K_ + k];
  }
  for (int i = tid; i < NFEAT * H_; i += 256) smem[i] = Meff[i];

  float feat[NFEAT];
  if (valid) {
#pragma unroll
    for (int k = 0; k < K_; ++k) {
      const float2 c = pts[ridx[k]];
      feat[2 * k]          = c.x;
      feat[2 * k + 1]      = c.y;
      feat[20 + 2 * k]     = c.x;
      feat[20 + 2 * k + 1] = c.y;
    }
#pragma unroll
    for (int p = 0; p < K_ - 1; ++p) {
#pragma unroll
      for (int u = 0; u < K_ - 1 - p; ++u) {
        const bool sw = feat[2 * u + 2] < feat[2 * u];
        const float ax = feat[2 * u], ay = feat[2 * u + 1];
        feat[2 * u]     = sw ? feat[2 * u + 2] : ax;
        feat[2 * u + 1] = sw ? feat[2 * u + 3] : ay;
        feat[2 * u + 2] = sw ? ax : feat[2 * u + 2];
        feat[2 * u + 3] = sw ? ay : feat[2 * u + 3];
      }
    }
#pragma unroll
    for (int p = 0; p < K_ - 1; ++p) {
#pragma unroll
      for (int u = 0; u < K_ - 1 - p; ++u) {
        const int e = 20 + 2 * u;
        const bool sw = feat[e + 3] < feat[e + 1];
        const float ax = feat[e], ay = feat[e + 1];
        feat[e]     = sw ? feat[e + 2] : ax;
        feat[e + 1] = sw ? feat[e + 3] : ay;
        feat[e + 2] = sw ? ax : feat[e + 2];
        feat[e + 3] = sw ? ay : feat[e + 3];
      }
    }
    feat[40] = px;
    feat[41] = py;
    feat[42] = 1.f;
  }
  __syncthreads();

  if (valid) {
    float* op = out + ((size_t)(b * N_ + n)) * H_;
#pragma unroll 2
    for (int gi = 0; gi < H_ / 8; ++gi) {
      const int g = gi * 8 + t;
      float acc = 0.f;
#pragma unroll
      for (int r = 0; r < NFEAT; ++r)
        acc = fmaf(feat[r], smem[r * H_ + g], acc);
      op[g] = acc;
    }
  }
}

extern "C" void kernel_launch(void* const* d_in, const int* in_sizes, int n_in,
                              void* d_out, int out_size, void* d_ws, size_t ws_size,
                              hipStream_t stream) {
  const float* x  = (const float*)d_in[0];
  const float* Wx = (const float*)d_in[1];
  const float* bx = (const float*)d_in[2];
  const float* Wy = (const float*)d_in[3];
  const float* by = (const float*)d_in[4];
  const float* W1 = (const float*)d_in[5];
  const float* b1 = (const float*)d_in[6];
  const float* W2 = (const float*)d_in[7];
  const float* b2 = (const float*)d_in[8];
  float* o = (float*)d_out;

  char* ws = (char*)d_ws;
  float*  Meff     = (float*)(ws + WS_MEFF);
  float2* spts_g   = (float2*)(ws + WS_SPTS);
  int*    skey_g   = (int*)(ws + WS_SKEY);
  int*    cstart_g = (int*)(ws + WS_CSTART);

  if (ws_size >= (size_t)WS_NEED) {
    prep<<<dim3(B_ + NFEAT), dim3(256), 0, stream>>>(
        x, Wx, bx, Wy, by, W1, b1, W2, b2, Meff, spts_g, skey_g, cstart_g);
    conv_knn<<<dim3((N_ + QPB - 1) / QPB, B_), dim3(QPB * TPQ), 0, stream>>>(
        spts_g, skey_g, cstart_g, Meff, o);
  } else {
    build_meff<<<dim3(NFEAT), dim3(H_), 0, stream>>>(Wx, bx, Wy, by, W1, b1, W2, b2, Meff);
    conv_emb_fb<<<dim3((N_ + 31) / 32, B_), dim3(256), 0, stream>>>(x, Meff, o);
  }
}

// Round 12
// 32.588 us; speedup vs baseline: 1.9198x; 1.9198x over previous
//
#include <hip/hip_runtime.h>
#include <cfloat>

#define B_ 32
#define N_ 1000
#define K_ 10
#define H_ 128
#define C_ 2
#define NFEAT 43
#define QPB 32      // queries per block
#define TPQ 8       // lanes per query (merge work scales with TPQ — keep 8)
#define G_ 16
#define CW (1.0f / 16.0f)
#define RING0 2     // 5x5 cell box

// ws layout (bytes): [0,22016) Meff | [22016,278016) spts float2
//                    | [278016,406016) skey int | [406016,438912) cellstart int
#define WS_MEFF   0
#define WS_SPTS   22016
#define WS_SKEY   278016
#define WS_CSTART 406016
#define WS_NEED   438912

// ---------------------------------------------------------------------------
// meff row computation (shared by prep and standalone build_meff)
// ---------------------------------------------------------------------------
__device__ __forceinline__ void meff_row(
    int r, int g, const float* __restrict__ Wx, const float* __restrict__ bx,
    const float* __restrict__ Wy, const float* __restrict__ by,
    const float* __restrict__ W1, const float* __restrict__ b1,
    const float* __restrict__ W2, const float* __restrict__ b2,
    float* __restrict__ M) {
  float acc = 0.f;
  if (r < 40) {
    const int rp = (r < 20) ? r : r - 20;
    const float* W = (r < 20) ? Wx : Wy;
    const int k = rp >> 1;
    const int c = rp & 1;
    const float* Wcol = W + c * K_ + k;
    for (int h = 0; h < H_; ++h)
      acc = fmaf(Wcol[h * C_ * K_], W2[h * H_ + g], acc);
  } else if (r < 42) {
    acc = W1[(r - 40) * H_ + g];
  } else {
    for (int h = 0; h < H_; ++h)
      acc = fmaf(bx[h] + by[h], W2[h * H_ + g], acc);
    acc += b1[g] + b2[g];
  }
  M[r * H_ + g] = acc;
}

__global__ __launch_bounds__(H_) void build_meff(
    const float* __restrict__ Wx, const float* __restrict__ bx,
    const float* __restrict__ Wy, const float* __restrict__ by,
    const float* __restrict__ W1, const float* __restrict__ b1,
    const float* __restrict__ W2, const float* __restrict__ b2,
    float* __restrict__ M) {
  meff_row(blockIdx.x, threadIdx.x, Wx, bx, Wy, by, W1, b1, W2, b2, M);
}

// ---------------------------------------------------------------------------
// Prep (fused): blocks 0..31 = per-batch counting sort; 32..74 = meff rows.
// ---------------------------------------------------------------------------
__global__ __launch_bounds__(256) void prep(
    const float* __restrict__ x,
    const float* __restrict__ Wx, const float* __restrict__ bx,
    const float* __restrict__ Wy, const float* __restrict__ by,
    const float* __restrict__ W1, const float* __restrict__ b1,
    const float* __restrict__ W2, const float* __restrict__ b2,
    float* __restrict__ Meff, float2* __restrict__ spts_g,
    int* __restrict__ skey_g, int* __restrict__ cstart_g) {
  const int tid = threadIdx.x;
  if (blockIdx.x >= B_) {
    const int r = blockIdx.x - B_;
    if (tid < H_) meff_row(r, tid, Wx, bx, Wy, by, W1, b1, W2, b2, Meff);
    return;
  }
  const int b = blockIdx.x;
  __shared__ float2 p[N_];
  __shared__ short  cidv[N_];
  __shared__ int    hist[G_ * G_], scn[G_ * G_], cur[G_ * G_];

  const float2* xb = (const float2*)(x + (size_t)b * N_ * C_);
  hist[tid] = 0;
  __syncthreads();
  for (int i = tid; i < N_; i += 256) {
    float2 v = xb[i];
    p[i] = v;
    int cxx = min(G_ - 1, max(0, (int)(v.x * (float)G_)));
    int cyy = min(G_ - 1, max(0, (int)(v.y * (float)G_)));
    int c = cyy * G_ + cxx;
    cidv[i] = (short)c;
    atomicAdd(&hist[c], 1);
  }
  __syncthreads();
  const int v = hist[tid];
  scn[tid] = v;
  __syncthreads();
  for (int off = 1; off < G_ * G_; off <<= 1) {
    int add = (tid >= off) ? scn[tid - off] : 0;
    __syncthreads();
    scn[tid] += add;
    __syncthreads();
  }
  const int excl = scn[tid] - v;
  cur[tid] = excl;
  cstart_g[b * (G_ * G_ + 1) + tid] = excl;
  if (tid == 0) cstart_g[b * (G_ * G_ + 1) + G_ * G_] = N_;
  __syncthreads();
  for (int i = tid; i < N_; i += 256) {
    int c = cidv[i];
    int pos = atomicAdd(&cur[c], 1);
    spts_g[b * N_ + pos] = p[i];
    skey_g[b * N_ + pos] = (i << 16) | pos;   // (orig_idx:16 | sorted_pos:16)
  }
}

// ---------------------------------------------------------------------------
// shuffle helper
// ---------------------------------------------------------------------------
__device__ __forceinline__ unsigned long long shflx64(unsigned long long v, int msk) {
  const unsigned lo = __shfl_xor((unsigned)(v & 0xffffffffull), msk, 64);
  const unsigned hi = __shfl_xor((unsigned)(v >> 32), msk, 64);
  return ((unsigned long long)hi << 32) | lo;
}

// branchless rank-insert (u64 key = (d2,orig,spos) => exact lax.top_k order)
#define INSERT_LDS(j)                                                          \
  {                                                                            \
    const float2 pp = spts[(j)];                                               \
    const float dx = __fsub_rn(px, pp.x);                                      \
    const float dy = __fsub_rn(py, pp.y);                                      \
    const float dd = __fadd_rn(__fmul_rn(dx, dx), __fmul_rn(dy, dy));          \
    const unsigned long long key =                                             \
        ((unsigned long long)__float_as_uint(dd) << 32) | (unsigned)skey[(j)]; \
    bool c[K_];                                                                \
    _Pragma("unroll") for (int kk = 0; kk < K_; ++kk) c[kk] = key < bk[kk];    \
    _Pragma("unroll") for (int kk = K_ - 1; kk >= 1; --kk)                     \
        bk[kk] = c[kk - 1] ? bk[kk - 1] : (c[kk] ? key : bk[kk]);              \
    bk[0] = c[0] ? key : bk[0];                                                \
  }

// Fused merge+gather: 10 rounds of cross-lane (8-lane) min of the sorted
// list heads; winner popped branchlessly; winner's coords broadcast-read
// from LDS straight into feat[] (static indices). Returns the 10th key.
#define MERGE_GATHER(tenth_out)                                                \
  {                                                                            \
    _Pragma("unroll") for (int s2 = 0; s2 < K_; ++s2) {                        \
      unsigned long long m = bk[0];                                            \
      unsigned long long o = shflx64(m, 1); m = (o < m) ? o : m;               \
      o = shflx64(m, 2); m = (o < m) ? o : m;                                  \
      o = shflx64(m, 4); m = (o < m) ? o : m;                                  \
      const bool pop = (bk[0] == m);                                           \
      _Pragma("unroll") for (int k2 = 0; k2 < K_ - 1; ++k2)                    \
          bk[k2] = pop ? bk[k2 + 1] : bk[k2];                                  \
      bk[K_ - 1] = pop ? ~0ull : bk[K_ - 1];                                   \
      const int spos = min((int)(m & 0xffffull), N_ - 1);                      \
      const float2 c = spts[spos];                                             \
      feat[2 * s2]          = c.x;                                             \
      feat[2 * s2 + 1]      = c.y;                                             \
      feat[20 + 2 * s2]     = c.x;                                             \
      feat[20 + 2 * s2 + 1] = c.y;                                             \
      if (s2 == K_ - 1) (tenth_out) = m;                                       \
    }                                                                          \
  }

// ---------------------------------------------------------------------------
// Kernel C: grid-pruned exact KNN (R7 structure) with fused min-reduce
// merge+gather. TPQ=8, QPB=32, LDS scan, M in LDS, (256,4).
// NOTE: no min-waves hint > 4 — VGPR caps below demand spill wholesale
// (R6/R8: WRITE_SIZE 16->76/108 MB).
// ---------------------------------------------------------------------------
__global__ __launch_bounds__(QPB * TPQ, 4) void conv_knn(
    const float2* __restrict__ spts_g, const int* __restrict__ skey_g,
    const int* __restrict__ cstart_g, const float* __restrict__ Meff,
    float* __restrict__ out) {
  __shared__ float2 spts[N_];                 // 8 KB
  __shared__ int    skey[N_];                 // 4 KB
  __shared__ int    cstart[G_ * G_ + 1];      // 1 KB
  __shared__ __align__(16) float smem[NFEAT * H_];  // 22 KB: M

  const int b = blockIdx.y, tid = threadIdx.x;
  const int q = tid >> 3, t = tid & 7;
  const int s = blockIdx.x * QPB + q;
  const bool valid = (s < N_);

  const float2* spg = spts_g + (size_t)b * N_;
  const int*    skg = skey_g + (size_t)b * N_;
  for (int i = tid; i < N_; i += QPB * TPQ) { spts[i] = spg[i]; skey[i] = skg[i]; }
  for (int i = tid; i < G_ * G_ + 1; i += QPB * TPQ)
    cstart[i] = cstart_g[b * (G_ * G_ + 1) + i];
  __syncthreads();

  float px = 0.f, py = 0.f;
  int cx = 0, cy = 0;
  if (valid) {
    px = spts[s].x; py = spts[s].y;
    cx = min(G_ - 1, max(0, (int)(px * (float)G_)));
    cy = min(G_ - 1, max(0, (int)(py * (float)G_)));
  }

  unsigned long long bk[K_];
#pragma unroll
  for (int k = 0; k < K_; ++k) bk[k] = ~0ull;

  // ---- single-pass 5x5 box scan, 8-way sliced per query ----
  const int X0 = max(cx - RING0, 0), X1 = min(cx + RING0, G_ - 1);
  const int Y0 = max(cy - RING0, 0), Y1 = min(cy + RING0, G_ - 1);
  if (valid) {
    for (int yy = Y0; yy <= Y1; ++yy) {
      const int s0 = cstart[yy * G_ + X0];
      const int s1 = cstart[yy * G_ + X1 + 1];
      for (int j = s0 + t; j < s1; j += TPQ) INSERT_LDS(j);
    }
  }

  // ---- fused merge + gather (unguarded: all 64 lanes shuffle) ----
  float feat[NFEAT];
  unsigned long long tenth = ~0ull;
  MERGE_GATHER(tenth);

  // ---- exact termination test (identical across a query's 8 lanes) ----
  bool done = true;
  if (valid) {
    const bool have10 = (tenth != ~0ull);
    const float tau = __uint_as_float((unsigned)(tenth >> 32));
    float R = 1e30f;
    if (X0 > 0)      R = fminf(R, px - (float)X0 * CW);
    if (X1 < G_ - 1) R = fminf(R, (float)(X1 + 1) * CW - px);
    if (Y0 > 0)      R = fminf(R, py - (float)Y0 * CW);
    if (Y1 < G_ - 1) R = fminf(R, (float)(Y1 + 1) * CW - py);
    const bool fullg = (X0 == 0) && (X1 == G_ - 1) && (Y0 == 0) && (Y1 == G_ - 1);
    const float Rs = R - 1e-6f;   // margin vs. cell-assignment rounding
    done = fullg || (have10 && Rs > 0.f && tau < Rs * Rs);
  }

  // ---- rare exact retry: full scan + re-merge (query-uniform predicate) ----
  if (__syncthreads_and(done ? 1 : 0) == 0) {
    const bool redo = valid && !done;
    if (redo) {
#pragma unroll
      for (int k = 0; k < K_; ++k) bk[k] = ~0ull;
      for (int j = t; j < N_; j += TPQ) INSERT_LDS(j);
    }
    if (redo) {          // all 8 lanes of a redo query enter together
      unsigned long long tenth2;
      MERGE_GATHER(tenth2);
    }
  }

  // ---- load M into LDS ----
  for (int i = tid; i < NFEAT * H_; i += QPB * TPQ) smem[i] = Meff[i];

  // ---- in-place stable bubble sorts on feat (all lanes redundant) ----
  if (valid) {
    // sort pairs (feat[2k],feat[2k+1]) by x  (strict swap => stable)
#pragma unroll
    for (int p = 0; p < K_ - 1; ++p) {
#pragma unroll
      for (int u = 0; u < K_ - 1 - p; ++u) {
        const bool sw = feat[2 * u + 2] < feat[2 * u];
        const float ax = feat[2 * u], ay = feat[2 * u + 1];
        feat[2 * u]     = sw ? feat[2 * u + 2] : ax;
        feat[2 * u + 1] = sw ? feat[2 * u + 3] : ay;
        feat[2 * u + 2] = sw ? ax : feat[2 * u + 2];
        feat[2 * u + 3] = sw ? ay : feat[2 * u + 3];
      }
    }
    // sort pairs (feat[20+2k],feat[20+2k+1]) by y
#pragma unroll
    for (int p = 0; p < K_ - 1; ++p) {
#pragma unroll
      for (int u = 0; u < K_ - 1 - p; ++u) {
        const int e = 20 + 2 * u;
        const bool sw = feat[e + 3] < feat[e + 1];
        const float ax = feat[e], ay = feat[e + 1];
        feat[e]     = sw ? feat[e + 2] : ax;
        feat[e + 1] = sw ? feat[e + 3] : ay;
        feat[e + 2] = sw ? ax : feat[e + 2];
        feat[e + 3] = sw ? ay : feat[e + 3];
      }
    }
    feat[40] = px;
    feat[41] = py;
    feat[42] = 1.f;
  }
  __syncthreads();

  // ---- fused affine: float4 LDS reads, g = j*32 + 4t (8 lanes span all 32
  // banks, queries broadcast); 128B-contiguous stores ----
  if (valid) {
    const int otar = skey[s] >> 16;
    float* op = out + ((size_t)(b * N_ + otar)) * H_;
    const float4* M4 = (const float4*)smem;   // row r = 32 float4
#pragma unroll
    for (int j = 0; j < 4; ++j) {
      float4 acc = make_float4(0.f, 0.f, 0.f, 0.f);
#pragma unroll
      for (int r = 0; r < NFEAT; ++r) {
        const float4 m = M4[r * 32 + j * 8 + t];
        acc.x = fmaf(feat[r], m.x, acc.x);
        acc.y = fmaf(feat[r], m.y, acc.y);
        acc.z = fmaf(feat[r], m.z, acc.z);
        acc.w = fmaf(feat[r], m.w, acc.w);
      }
      *(float4*)&op[j * 32 + 4 * t] = acc;
    }
  }
}
#undef INSERT_LDS
#undef MERGE_GATHER

// ---------------------------------------------------------------------------
// No-workspace fallback (round-2 kernel).
// ---------------------------------------------------------------------------
#define LSTRIDE 170
__global__ __launch_bounds__(256, 4) void conv_emb_fb(
    const float* __restrict__ x, const float* __restrict__ Meff,
    float* __restrict__ out) {
  __shared__ float2 pts[N_];
  __shared__ float  smem[NFEAT * H_];
  __shared__ int    midx[32 * K_];

  const int b   = blockIdx.y;
  const int tid = threadIdx.x;
  const int q   = tid >> 3;
  const int t   = tid & 7;
  const int n   = blockIdx.x * 32 + q;
  const bool valid = (n < N_);

  const float2* xb = (const float2*)(x + (size_t)b * N_ * C_);
  for (int i = tid; i < N_; i += 256) pts[i] = xb[i];
  __syncthreads();

  float px = 0.f, py = 0.f;
  if (valid) { px = pts[n].x; py = pts[n].y; }

  float bd[K_]; int bi[K_];
#pragma unroll
  for (int k = 0; k < K_; ++k) { bd[k] = FLT_MAX; bi[k] = 0; }

#pragma unroll 2
  for (int m = 0; m < N_ / 8; ++m) {
    const int j = t + m * 8;
    const float2 p = pts[j];
    const float dx = __fsub_rn(px, p.x);
    const float dy = __fsub_rn(py, p.y);
    const float d  = __fadd_rn(__fmul_rn(dx, dx), __fmul_rn(dy, dy));
    bool c[K_];
#pragma unroll
    for (int s = 0; s < K_; ++s) c[s] = d < bd[s];
#pragma unroll
    for (int s = K_ - 1; s >= 1; --s) {
      bd[s] = c[s - 1] ? bd[s - 1] : (c[s] ? d : bd[s]);
      bi[s] = c[s - 1] ? bi[s - 1] : (c[s] ? j : bi[s]);
    }
    bd[0] = c[0] ? d : bd[0];
    bi[0] = c[0] ? j : bi[0];
  }

  const int lbase = q * LSTRIDE + t * 2 * K_;
#pragma unroll
  for (int e = 0; e < K_; ++e) {
    smem[lbase + 2 * e]     = bd[e];
    smem[lbase + 2 * e + 1] = __int_as_float(bi[e]);
  }
  __syncthreads();

  if (t == 0 && valid) {
    int cc[8];
#pragma unroll
    for (int tt = 0; tt < 8; ++tt) cc[tt] = 0;
    const int mb = q * LSTRIDE;
#pragma unroll
    for (int s = 0; s < K_; ++s) {
      float bdv = FLT_MAX; int biv = 0x7fffffff; int bt = 0;
#pragma unroll
      for (int tt = 0; tt < 8; ++tt) {
        const int off = mb + tt * 2 * K_ + cc[tt] * 2;
        const float hd = smem[off];
        const int   hi = __float_as_int(smem[off + 1]);
        const bool take = (hd < bdv) || ((hd == bdv) && (hi < biv));
        bdv = take ? hd : bdv;
        biv = take ? hi : biv;
        bt  = take ? tt : bt;
      }
      midx[q * K_ + s] = biv;
#pragma unroll
      for (int tt = 0; tt < 8; ++tt) cc[tt] += (bt == tt) ? 1 : 0;
    }
  }
  __syncthreads();

  int ridx[K_];
  if (valid) {
#pragma unroll
    for (int k = 0; k < K_; ++k) ridx[k] = midx[q * K_ + k];
  }
  for (int i = tid; i < NFEAT * H_; i += 256) smem[i] = Meff[i];

  float feat[NFEAT];
  if (valid) {
#pragma unroll
    for (int k = 0; k < K_; ++k) {
      const float2 c = pts[ridx[k]];
      feat[2 * k]          = c.x;
      feat[2 * k + 1]      = c.y;
      feat[20 + 2 * k]     = c.x;
      feat[20 + 2 * k + 1] = c.y;
    }
#pragma unroll
    for (int p = 0; p < K_ - 1; ++p) {
#pragma unroll
      for (int u = 0; u < K_ - 1 - p; ++u) {
        const bool sw = feat[2 * u + 2] < feat[2 * u];
        const float ax = feat[2 * u], ay = feat[2 * u + 1];
        feat[2 * u]     = sw ? feat[2 * u + 2] : ax;
        feat[2 * u + 1] = sw ? feat[2 * u + 3] : ay;
        feat[2 * u + 2] = sw ? ax : feat[2 * u + 2];
        feat[2 * u + 3] = sw ? ay : feat[2 * u + 3];
      }
    }
#pragma unroll
    for (int p = 0; p < K_ - 1; ++p) {
#pragma unroll
      for (int u = 0; u < K_ - 1 - p; ++u) {
        const int e = 20 + 2 * u;
        const bool sw = feat[e + 3] < feat[e + 1];
        const float ax = feat[e], ay = feat[e + 1];
        feat[e]     = sw ? feat[e + 2] : ax;
        feat[e + 1] = sw ? feat[e + 3] : ay;
        feat[e + 2] = sw ? ax : feat[e + 2];
        feat[e + 3] = sw ? ay : feat[e + 3];
      }
    }
    feat[40] = px;
    feat[41] = py;
    feat[42] = 1.f;
  }
  __syncthreads();

  if (valid) {
    float* op = out + ((size_t)(b * N_ + n)) * H_;
#pragma unroll 2
    for (int gi = 0; gi < H_ / 8; ++gi) {
      const int g = gi * 8 + t;
      float acc = 0.f;
#pragma unroll
      for (int r = 0; r < NFEAT; ++r)
        acc = fmaf(feat[r], smem[r * H_ + g], acc);
      op[g] = acc;
    }
  }
}

extern "C" void kernel_launch(void* const* d_in, const int* in_sizes, int n_in,
                              void* d_out, int out_size, void* d_ws, size_t ws_size,
                              hipStream_t stream) {
  const float* x  = (const float*)d_in[0];
  const float* Wx = (const float*)d_in[1];
  const float* bx = (const float*)d_in[2];
  const float* Wy = (const float*)d_in[3];
  const float* by = (const float*)d_in[4];
  const float* W1 = (const float*)d_in[5];
  const float* b1 = (const float*)d_in[6];
  const float* W2 = (const float*)d_in[7];
  const float* b2 = (const float*)d_in[8];
  float* o = (float*)d_out;

  char* ws = (char*)d_ws;
  float*  Meff     = (float*)(ws + WS_MEFF);
  float2* spts_g   = (float2*)(ws + WS_SPTS);
  int*    skey_g   = (int*)(ws + WS_SKEY);
  int*    cstart_g = (int*)(ws + WS_CSTART);

  if (ws_size >= (size_t)WS_NEED) {
    prep<<<dim3(B_ + NFEAT), dim3(256), 0, stream>>>(
        x, Wx, bx, Wy, by, W1, b1, W2, b2, Meff, spts_g, skey_g, cstart_g);
    conv_knn<<<dim3((N_ + QPB - 1) / QPB, B_), dim3(QPB * TPQ), 0, stream>>>(
        spts_g, skey_g, cstart_g, Meff, o);
  } else {
    build_meff<<<dim3(NFEAT), dim3(H_), 0, stream>>>(Wx, bx, Wy, by, W1, b1, W2, b2, Meff);
    conv_emb_fb<<<dim3((N_ + 31) / 32, B_), dim3(256), 0, stream>>>(x, Meff, o);
  }
}